// Round 17
// baseline (541.420 us; speedup 1.0000x reference)
//
#include <hip/hip_runtime.h>
#include <hip/hip_bf16.h>
#include <stdint.h>
#include <math.h>

// ---------------- types / helpers ----------------
typedef __attribute__((ext_vector_type(8))) short bf16x8;   // 8 bf16 in 4 VGPRs
typedef __attribute__((ext_vector_type(4))) float f32x4;

#define AS1 __attribute__((address_space(1)))
#define AS3 __attribute__((address_space(3)))

__device__ __forceinline__ ushort f2bf(float f) {
  union { float f; uint32_t u; } in; in.f = f;
  uint32_t u = in.u;
  uint32_t r = u + 0x7fffu + ((u >> 16) & 1u);   // RNE; inputs finite
  return (ushort)(r >> 16);
}
__device__ __forceinline__ float bf2f(ushort h) {
  union { uint32_t u; float f; } out; out.u = ((uint32_t)h) << 16;
  return out.f;
}

// ---------------- cast f32 -> bf16 (vectorized) ----------------
__global__ __launch_bounds__(256)
void cast_f32_bf16(const float4* __restrict__ in, ushort4* __restrict__ out, int n4) {
  int i = blockIdx.x * blockDim.x + threadIdx.x;
  int stride = gridDim.x * blockDim.x;
  for (; i < n4; i += stride) {
    float4 v = in[i];
    ushort4 o;
    o.x = f2bf(v.x); o.y = f2bf(v.y); o.z = f2bf(v.z); o.w = f2bf(v.w);
    out[i] = o;
  }
}

// ---------------- V (B,LK,D) f32 -> Vt (B,D,LK) bf16 ----------------
__global__ __launch_bounds__(256)
void transpose_cast_v(const float* __restrict__ V, ushort* __restrict__ Vt) {
  __shared__ ushort tile[32][33];                // +1 pad: no bank conflicts
  const int b  = blockIdx.z;
  const int k0 = blockIdx.x * 32;
  const int d0 = blockIdx.y * 32;
  const int tx = threadIdx.x;                    // 0..31
  const int ty = threadIdx.y;                    // 0..7
  const float* Vb = V + ((size_t)b * 1024 + k0) * 1024 + d0;
  #pragma unroll
  for (int r = 0; r < 4; ++r) {
    int k = ty * 4 + r;
    tile[k][tx] = f2bf(Vb[(size_t)k * 1024 + tx]);
  }
  __syncthreads();
  ushort* Vtb = Vt + ((size_t)b * 1024 + d0) * 1024 + k0;
  #pragma unroll
  for (int r = 0; r < 4; ++r) {
    int d = ty * 4 + r;
    Vtb[(size_t)d * 1024 + tx] = tile[tx][d];
  }
}

// ---------------- masked softmax over each (b,q) row of S (bf16 in/out) ----
__global__ __launch_bounds__(256)
void softmax_mask(const ushort* __restrict__ S, ushort* __restrict__ P,
                  const float* __restrict__ mask) {
  const int rowId = blockIdx.x;                  // 0..B*LQ-1
  const int b = rowId >> 10;                     // LQ = 1024
  const ushort4* srow = (const ushort4*)(S + (size_t)rowId * 1024);
  const float4* mrow = (const float4*)(mask + (size_t)b * 1024);
  const int t = threadIdx.x;
  const int wid = t >> 6, lane = t & 63;

  ushort4 sv = srow[t];
  float4 mv = mrow[t];
  float s[4] = {bf2f(sv.x), bf2f(sv.y), bf2f(sv.z), bf2f(sv.w)};
  float m[4] = {mv.x, mv.y, mv.z, mv.w};

  float mx = -INFINITY;
  #pragma unroll
  for (int i = 0; i < 4; ++i) if (m[i] != 0.f) mx = fmaxf(mx, s[i]);
  #pragma unroll
  for (int off = 32; off > 0; off >>= 1)
    mx = fmaxf(mx, __shfl_xor(mx, off));

  __shared__ float wred[4][2];
  if (lane == 0) wred[wid][0] = mx;
  __syncthreads();
  float M = fmaxf(fmaxf(wred[0][0], wred[1][0]), fmaxf(wred[2][0], wred[3][0]));

  float e[4]; float sum = 0.f;
  #pragma unroll
  for (int i = 0; i < 4; ++i) {
    e[i] = (m[i] != 0.f) ? __expf(s[i] - M) : 0.f;
    sum += e[i];
  }
  #pragma unroll
  for (int off = 32; off > 0; off >>= 1)
    sum += __shfl_xor(sum, off);
  if (lane == 0) wred[wid][1] = sum;
  __syncthreads();
  float Z = wred[0][1] + wred[1][1] + wred[2][1] + wred[3][1];
  float inv = (Z > 0.f) ? 1.f / Z : 0.f;

  ushort4 o;
  o.x = f2bf(e[0] * inv); o.y = f2bf(e[1] * inv);
  o.z = f2bf(e[2] * inv); o.w = f2bf(e[3] * inv);
  ((ushort4*)(P + (size_t)rowId * 1024))[t] = o;
}

// ---------------- GEMM 128x256, BK=64, 8 waves, single-buffer -------------
// C = A(Mx1024,row) * Bt(1024x1024,row)^T.
// r9 structure with ONE change: asymmetric 128x256 tile (A 16KB + B 32KB
// per kt = 48KB staged for 4.19 MFLOP = 87 FLOP/B vs r9's 64).  512 thr,
// 8 waves as 2x4; each wave computes the SAME 64x64 sub-tile as r9
// (acc[4][4], ~120 unified regs).  2 blocks/CU (96KB LDS) keeps r9's
// 16 waves/CU and 4 waves/SIMD; per-CU slot staging drops 128->96KB.
// Lockstep K-walk kept (r14: stagger broke L2 sharing).  No inline asm.
// + T2 swizzle (0 conflicts): byte involution y ^= (y>>3)&0x70 (rule #21).
// + T1 XCD remap (all grids here are multiples of 8).
// EPI: 0 -> outBf = bf16(acc*scale)                              (S)
//      1 -> outBf = bf16(bf2f(auxBf) + acc)                      (X = Q + PV)
//      2 -> outBf = bf16(relu(acc + bias[col]))                  (FFN1 -> h)
//      3 -> outF  = acc + bias[col] + bf2f(auxBf)                (FFN2 + residual)
template<int EPI>
__global__ __launch_bounds__(512, 4)
void gemm128x256(const ushort* __restrict__ A, const ushort* __restrict__ Bt,
                 size_t aBatch, size_t bBatch, size_t oBatch,
                 float scale,
                 ushort* outBf, float* outF, const ushort* auxBf,
                 const float* __restrict__ bias)
{
  constexpr int K = 1024, N = 1024, NT = 16;    // K-tiles of 64
  __shared__ ushort lsA[128 * 64];              // 16 KiB
  __shared__ ushort lsB[256 * 64];              // 32 KiB
  const int t = threadIdx.x;
  const int w = t >> 6, lane = t & 63;
  const int wr = w >> 2, wc = w & 3;            // 2 x 4 waves -> 64x64 per wave
  const int lr16 = lane & 15, kg = lane >> 4;

  // T1: XCD-aware bijective remap (nwg is a multiple of 8 for all our grids)
  const unsigned nx = gridDim.x, ny = gridDim.y;
  unsigned flat = blockIdx.x + nx * (blockIdx.y + ny * blockIdx.z);
  const unsigned nwg = nx * ny * gridDim.z;
  const unsigned cpx = nwg >> 3;
  unsigned nf = (flat & 7u) * cpx + (flat >> 3);
  const unsigned bxi = nf % nx;
  const unsigned rest = nf / nx;
  const unsigned byi = rest % ny;
  const unsigned bz = rest / ny;
  const int m0 = byi * 128, n0 = bxi * 256;

  const char* Ab = (const char*)(A + (size_t)bz * aBatch + (size_t)m0 * K);
  const char* Bb = (const char*)(Bt + (size_t)bz * bBatch + (size_t)n0 * K);

  // staging decode (512 threads x 16B = 8KB per chunk-round):
  // A: 2 chunks (16KB); B: 4 chunks (32KB).  Rows are 128B (64 bf16).
  // lds-linear byte y -> unswizzled tile byte tb = y ^ ((y>>3)&0x70);
  // global = (tb>>7)*2048 + (tb&127) + kt*128.
  int gA[2], lA[2], gB[4], lB[4];
  #pragma unroll
  for (int i = 0; i < 2; ++i) {
    int y = (w * 2 + i) * 1024 + lane * 16;
    int tb = y ^ ((y >> 3) & 0x70);
    gA[i] = (tb >> 7) * 2048 + (tb & 127);
    lA[i] = (w * 2 + i) * 1024;                 // wave-uniform (+lane*16 by HW)
  }
  #pragma unroll
  for (int i = 0; i < 4; ++i) {
    int y = (w * 4 + i) * 1024 + lane * 16;
    int tb = y ^ ((y >> 3) & 0x70);
    gB[i] = (tb >> 7) * 2048 + (tb & 127);
    lB[i] = (w * 4 + i) * 1024;
  }

  // fragment reads (swizzled): row*128 + ((ks*4+kg)^(row&7))*16, row&7 = lr16&7
  const int sl0 = (kg ^ (lr16 & 7)) << 4;
  const int aBase = (wr * 64 + lr16) * 128 + sl0;
  const int bBase = (wc * 64 + lr16) * 128 + sl0;

  f32x4 acc[4][4];
  #pragma unroll
  for (int i = 0; i < 4; ++i)
    #pragma unroll
    for (int j = 0; j < 4; ++j)
      acc[i][j] = (f32x4){0.f, 0.f, 0.f, 0.f};

  #pragma unroll 1
  for (int kt = 0; kt < NT; ++kt) {
    // stage tile kt into the single buffer (2 A + 4 B gload_lds w=16/thread)
    #pragma unroll
    for (int i = 0; i < 2; ++i)
      __builtin_amdgcn_global_load_lds(
        (const AS1 void*)(Ab + gA[i] + kt * 128),
        (AS3 void*)((char*)lsA + lA[i]), 16, 0, 0);
    #pragma unroll
    for (int i = 0; i < 4; ++i)
      __builtin_amdgcn_global_load_lds(
        (const AS1 void*)(Bb + gB[i] + kt * 128),
        (AS3 void*)((char*)lsB + lB[i]), 16, 0, 0);
    __syncthreads();                            // compiler: vmcnt(0) drain

    #pragma unroll
    for (int ks = 0; ks < 2; ++ks) {
      bf16x8 af[4], bfv[4];
      #pragma unroll
      for (int mi = 0; mi < 4; ++mi)
        af[mi] = *(const bf16x8*)((const char*)lsA + ((aBase + mi * 2048) ^ (ks * 64)));
      #pragma unroll
      for (int ni = 0; ni < 4; ++ni)
        bfv[ni] = *(const bf16x8*)((const char*)lsB + ((bBase + ni * 2048) ^ (ks * 64)));
      #pragma unroll
      for (int mi = 0; mi < 4; ++mi)
        #pragma unroll
        for (int ni = 0; ni < 4; ++ni)
          acc[mi][ni] = __builtin_amdgcn_mfma_f32_16x16x32_bf16(
              af[mi], bfv[ni], acc[mi][ni], 0, 0, 0);
    }
    __syncthreads();                            // reads drained before re-stage
  }

  // epilogue: C/D layout col=lane&15, row=(lane>>4)*4+j  [m89-verified]
  const int lr4 = kg * 4;
  #pragma unroll
  for (int mi = 0; mi < 4; ++mi) {
    #pragma unroll
    for (int ni = 0; ni < 4; ++ni) {
      int row = m0 + wr * 64 + mi * 16 + lr4;
      int col = n0 + wc * 64 + ni * 16 + lr16;
      size_t o = (size_t)bz * oBatch + (size_t)row * N + col;
      f32x4 v = acc[mi][ni];
      #pragma unroll
      for (int j = 0; j < 4; ++j) {
        size_t oo = o + (size_t)j * N;
        float x = v[j];
        if (EPI == 0) {
          outBf[oo] = f2bf(x * scale);
        } else if (EPI == 1) {
          outBf[oo] = f2bf(bf2f(auxBf[oo]) + x);
        } else if (EPI == 2) {
          float h = x + bias[col];
          h = h > 0.f ? h : 0.f;
          outBf[oo] = f2bf(h);
        } else {
          outF[oo] = x + bias[col] + bf2f(auxBf[oo]);
        }
      }
    }
  }
}

// ---------------- launch ----------------
extern "C" void kernel_launch(void* const* d_in, const int* in_sizes, int n_in,
                              void* d_out, int out_size, void* d_ws, size_t ws_size,
                              hipStream_t stream) {
  (void)in_sizes; (void)n_in; (void)out_size; (void)ws_size;
  const float* Q  = (const float*)d_in[0];
  const float* Km = (const float*)d_in[1];
  const float* V  = (const float*)d_in[2];
  const float* Vm = (const float*)d_in[3];
  const float* W1 = (const float*)d_in[4];
  const float* b1 = (const float*)d_in[5];
  const float* W2 = (const float*)d_in[6];
  const float* b2 = (const float*)d_in[7];
  float* out = (float*)d_out;

  const int LQ = 1024, LK = 1024, D = 1024;
  const size_t NQ = (size_t)32 * LQ * D;            // 33.5M elems

  // workspace layout (MiB offsets): Qb 0..64, Kb/hb 64..128, Vt 128..192,
  // Sb 192..256, P 256..320, Xb 320..384, W1b 384..386, W2b 386..388
  char* ws = (char*)d_ws;
  ushort* Qb  = (ushort*)(ws);
  ushort* Kb  = (ushort*)(ws + ((size_t)64 << 20));
  ushort* hb  = Kb;                                  // reuse (Kb dead after S-GEMM)
  ushort* Vt  = (ushort*)(ws + ((size_t)128 << 20));
  ushort* Sb  = (ushort*)(ws + ((size_t)192 << 20));
  ushort* P   = (ushort*)(ws + ((size_t)256 << 20));
  ushort* Xb  = (ushort*)(ws + ((size_t)320 << 20));
  ushort* W1b = (ushort*)(ws + ((size_t)384 << 20));
  ushort* W2b = (ushort*)(ws + ((size_t)386 << 20));

  const float inv_scale = 1.0f / (sqrtf(1024.0f) + 1e-8f);

  cast_f32_bf16<<<2048, 256, 0, stream>>>((const float4*)Q,  (ushort4*)Qb, (int)(NQ / 4));
  cast_f32_bf16<<<2048, 256, 0, stream>>>((const float4*)Km, (ushort4*)Kb, (int)(NQ / 4));
  cast_f32_bf16<<<256, 256, 0, stream>>>((const float4*)W1, (ushort4*)W1b, (1024 * 1024) / 4);
  cast_f32_bf16<<<256, 256, 0, stream>>>((const float4*)W2, (ushort4*)W2b, (1024 * 1024) / 4);
  transpose_cast_v<<<dim3(32, 32, 32), dim3(32, 8), 0, stream>>>(V, Vt);

  // Sb = bf16((Qb @ Kb^T) * inv_scale), batched over 32
  gemm128x256<0><<<dim3(4, 8, 32), 512, 0, stream>>>(
      Qb, Kb,
      (size_t)LQ * D, (size_t)LK * D, (size_t)LQ * LK,
      inv_scale, Sb, nullptr, nullptr, nullptr);

  softmax_mask<<<32768, 256, 0, stream>>>(Sb, P, Vm);

  // Xb = bf16(Qb + P @ V)
  gemm128x256<1><<<dim3(4, 8, 32), 512, 0, stream>>>(
      P, Vt,
      (size_t)LQ * LK, (size_t)D * LK, (size_t)LQ * D,
      1.f, Xb, nullptr, Qb, nullptr);

  // hb = bf16(relu(Xb @ W1^T + b1)); M = 32768 folded into blockIdx.y
  gemm128x256<2><<<dim3(4, 256, 1), 512, 0, stream>>>(
      Xb, W1b, 0, 0, 0,
      1.f, hb, nullptr, nullptr, b1);

  // out = hb @ W2^T + b2 + Xb
  gemm128x256<3><<<dim3(4, 256, 1), 512, 0, stream>>>(
      hb, W2b, 0, 0, 0,
      1.f, nullptr, out, Xb, b2);
}

// Round 18
// 531.385 us; speedup vs baseline: 1.0189x; 1.0189x over previous
//
#include <hip/hip_runtime.h>
#include <hip/hip_bf16.h>
#include <stdint.h>
#include <math.h>

// ---------------- types / helpers ----------------
typedef __attribute__((ext_vector_type(8))) short bf16x8;   // 8 bf16 in 4 VGPRs
typedef __attribute__((ext_vector_type(4))) float f32x4;

#define AS1 __attribute__((address_space(1)))
#define AS3 __attribute__((address_space(3)))

__device__ __forceinline__ ushort f2bf(float f) {
  union { float f; uint32_t u; } in; in.f = f;
  uint32_t u = in.u;
  uint32_t r = u + 0x7fffu + ((u >> 16) & 1u);   // RNE; inputs finite
  return (ushort)(r >> 16);
}
__device__ __forceinline__ float bf2f(ushort h) {
  union { uint32_t u; float f; } out; out.u = ((uint32_t)h) << 16;
  return out.f;
}

// ---------------- paired cast f32 -> bf16 (two tensors, one launch) -------
__global__ __launch_bounds__(256)
void cast2_f32_bf16(const float4* __restrict__ inA, ushort4* __restrict__ outA,
                    const float4* __restrict__ inB, ushort4* __restrict__ outB,
                    int n4) {
  const float4* in = blockIdx.z ? inB : inA;
  ushort4* out = blockIdx.z ? outB : outA;
  int i = blockIdx.x * blockDim.x + threadIdx.x;
  int stride = gridDim.x * blockDim.x;
  for (; i < n4; i += stride) {
    float4 v = in[i];
    ushort4 o;
    o.x = f2bf(v.x); o.y = f2bf(v.y); o.z = f2bf(v.z); o.w = f2bf(v.w);
    out[i] = o;
  }
}

// ---------------- V (B,LK,D) f32 -> Vt (B,D,LK) bf16, ushort4 stores ------
// Load phase unchanged (coalesced f32).  Store phase re-gathered so each
// lane writes ushort4 (8 B) along k: 4x wider than the old 2-B scalar
// stores (G13: vectorize ALL memory-bound kernels, not just GEMM).
__global__ __launch_bounds__(256)
void transpose_cast_v(const float* __restrict__ V, ushort* __restrict__ Vt) {
  __shared__ ushort tile[32][36];                // 36-pad: store-gather spread
  const int b  = blockIdx.z;
  const int k0 = blockIdx.x * 32;
  const int d0 = blockIdx.y * 32;
  const int tx = threadIdx.x;                    // 0..31
  const int ty = threadIdx.y;                    // 0..7
  const float* Vb = V + ((size_t)b * 1024 + k0) * 1024 + d0;
  #pragma unroll
  for (int r = 0; r < 4; ++r) {
    int k = ty * 4 + r;
    tile[k][tx] = f2bf(Vb[(size_t)k * 1024 + tx]);
  }
  __syncthreads();
  // store: flat t -> d = t>>3 (0..31), kq = t&7; write ushort4 at [d][kq*4]
  const int t = ty * 32 + tx;
  const int d = t >> 3, kq = t & 7;
  ushort4 o;
  o.x = tile[kq * 4 + 0][d];
  o.y = tile[kq * 4 + 1][d];
  o.z = tile[kq * 4 + 2][d];
  o.w = tile[kq * 4 + 3][d];
  ushort* Vtb = Vt + ((size_t)b * 1024 + d0) * 1024 + k0;
  *(ushort4*)(Vtb + (size_t)d * 1024 + kq * 4) = o;
}

// ---------------- masked softmax over each (b,q) row of S (bf16 in/out) ----
__global__ __launch_bounds__(256)
void softmax_mask(const ushort* __restrict__ S, ushort* __restrict__ P,
                  const float* __restrict__ mask) {
  const int rowId = blockIdx.x;                  // 0..B*LQ-1
  const int b = rowId >> 10;                     // LQ = 1024
  const ushort4* srow = (const ushort4*)(S + (size_t)rowId * 1024);
  const float4* mrow = (const float4*)(mask + (size_t)b * 1024);
  const int t = threadIdx.x;
  const int wid = t >> 6, lane = t & 63;

  ushort4 sv = srow[t];
  float4 mv = mrow[t];
  float s[4] = {bf2f(sv.x), bf2f(sv.y), bf2f(sv.z), bf2f(sv.w)};
  float m[4] = {mv.x, mv.y, mv.z, mv.w};

  float mx = -INFINITY;
  #pragma unroll
  for (int i = 0; i < 4; ++i) if (m[i] != 0.f) mx = fmaxf(mx, s[i]);
  #pragma unroll
  for (int off = 32; off > 0; off >>= 1)
    mx = fmaxf(mx, __shfl_xor(mx, off));

  __shared__ float wred[4][2];
  if (lane == 0) wred[wid][0] = mx;
  __syncthreads();
  float M = fmaxf(fmaxf(wred[0][0], wred[1][0]), fmaxf(wred[2][0], wred[3][0]));

  float e[4]; float sum = 0.f;
  #pragma unroll
  for (int i = 0; i < 4; ++i) {
    e[i] = (m[i] != 0.f) ? __expf(s[i] - M) : 0.f;
    sum += e[i];
  }
  #pragma unroll
  for (int off = 32; off > 0; off >>= 1)
    sum += __shfl_xor(sum, off);
  if (lane == 0) wred[wid][1] = sum;
  __syncthreads();
  float Z = wred[0][1] + wred[1][1] + wred[2][1] + wred[3][1];
  float inv = (Z > 0.f) ? 1.f / Z : 0.f;

  ushort4 o;
  o.x = f2bf(e[0] * inv); o.y = f2bf(e[1] * inv);
  o.z = f2bf(e[2] * inv); o.w = f2bf(e[3] * inv);
  ((ushort4*)(P + (size_t)rowId * 1024))[t] = o;
}

// ---------------- GEMM 128x128, BK=64, 4 waves, single-buffer (r9/r16) ----
// C = A(Mx1024,row) * Bt(1024x1024,row)^T.
// The measured optimum of this search (536-537 us total, verified twice):
// - 32 KiB LDS single-buffer, 2 barriers/K-tile, no inline asm.
// - __launch_bounds__(256,4): unified VGPR+AGPR = ~120 <= 128.  Bracketed:
//   5 blocks (cap 102) spills acc (r15); big-LDS structures serialize (r3-r8).
// - lockstep K-walk shares L2 K-panels across co-resident blocks (r14).
// - epoch ~2510 cyc is invariant to schedule/staging/occupancy/tile-aspect
//   (r3-r17): latency/serialization floor of this compiler+structure.
// + T2 swizzle (0 conflicts): y ^= (y>>3)&0x70 (rule #21 pairing).
// + T1 XCD remap (all grids here are multiples of 8).
// EPI: 0 -> outBf = bf16(acc*scale)                              (S)
//      1 -> outBf = bf16(bf2f(auxBf) + acc)                      (X = Q + PV)
//      2 -> outBf = bf16(relu(acc + bias[col]))                  (FFN1 -> h)
//      3 -> outF  = acc + bias[col] + bf2f(auxBf)                (FFN2 + residual)
template<int EPI>
__global__ __launch_bounds__(256, 4)
void gemm128(const ushort* __restrict__ A, const ushort* __restrict__ Bt,
             size_t aBatch, size_t bBatch, size_t oBatch,
             float scale,
             ushort* outBf, float* outF, const ushort* auxBf,
             const float* __restrict__ bias)
{
  constexpr int K = 1024, N = 1024, NT = 16;    // K-tiles of 64
  __shared__ ushort lsA[128 * 64];              // 16 KiB
  __shared__ ushort lsB[128 * 64];              // 16 KiB
  const int t = threadIdx.x;
  const int w = t >> 6, lane = t & 63;
  const int wr = w >> 1, wc = w & 1;            // 2 x 2 waves -> 64x64 per wave
  const int lr16 = lane & 15, kg = lane >> 4;

  // T1: XCD-aware bijective remap (nwg is a multiple of 8 for all our grids)
  const unsigned nx = gridDim.x, ny = gridDim.y;
  unsigned flat = blockIdx.x + nx * (blockIdx.y + ny * blockIdx.z);
  const unsigned nwg = nx * ny * gridDim.z;
  const unsigned cpx = nwg >> 3;
  unsigned nf = (flat & 7u) * cpx + (flat >> 3);
  const unsigned bxi = nf % nx;
  const unsigned rest = nf / nx;
  const unsigned byi = rest % ny;
  const unsigned bz = rest / ny;
  const int m0 = byi * 128, n0 = bxi * 128;

  const char* Ab = (const char*)(A + (size_t)bz * aBatch + (size_t)m0 * K);
  const char* Bb = (const char*)(Bt + (size_t)bz * bBatch + (size_t)n0 * K);

  // staging decode: 4 chunks of 16B/lane per matrix per thread (16 KiB tile).
  // lds-linear byte y = (w*4+i)*1024 + lane*16; unswizzled tile byte
  // tb = y ^ ((y>>3)&0x70); global = (tb>>7)*2048 + (tb&127) + kt*128.
  int gOff[4], lOff[4];
  #pragma unroll
  for (int i = 0; i < 4; ++i) {
    int y = (w * 4 + i) * 1024 + lane * 16;
    int tb = y ^ ((y >> 3) & 0x70);
    gOff[i] = (tb >> 7) * 2048 + (tb & 127);
    lOff[i] = (w * 4 + i) * 1024;               // wave-uniform LDS base (+lane*16 by HW)
  }

  // fragment reads (swizzled): row*128 + ((ks*4+kg)^(row&7))*16, row&7 = lr16&7
  const int sl0 = (kg ^ (lr16 & 7)) << 4;
  const int aBase = (wr * 64 + lr16) * 128 + sl0;
  const int bBase = (wc * 64 + lr16) * 128 + sl0;

  f32x4 acc[4][4];
  #pragma unroll
  for (int i = 0; i < 4; ++i)
    #pragma unroll
    for (int j = 0; j < 4; ++j)
      acc[i][j] = (f32x4){0.f, 0.f, 0.f, 0.f};

  #pragma unroll 1
  for (int kt = 0; kt < NT; ++kt) {
    // stage tile kt into the single buffer (4+4 gload_lds w=16 per thread)
    #pragma unroll
    for (int i = 0; i < 4; ++i)
      __builtin_amdgcn_global_load_lds(
        (const AS1 void*)(Ab + gOff[i] + kt * 128),
        (AS3 void*)((char*)lsA + lOff[i]), 16, 0, 0);
    #pragma unroll
    for (int i = 0; i < 4; ++i)
      __builtin_amdgcn_global_load_lds(
        (const AS1 void*)(Bb + gOff[i] + kt * 128),
        (AS3 void*)((char*)lsB + lOff[i]), 16, 0, 0);
    __syncthreads();                            // compiler: vmcnt(0) drain

    #pragma unroll
    for (int ks = 0; ks < 2; ++ks) {
      bf16x8 af[4], bfv[4];
      #pragma unroll
      for (int mi = 0; mi < 4; ++mi)
        af[mi] = *(const bf16x8*)((const char*)lsA + ((aBase + mi * 2048) ^ (ks * 64)));
      #pragma unroll
      for (int ni = 0; ni < 4; ++ni)
        bfv[ni] = *(const bf16x8*)((const char*)lsB + ((bBase + ni * 2048) ^ (ks * 64)));
      #pragma unroll
      for (int mi = 0; mi < 4; ++mi)
        #pragma unroll
        for (int ni = 0; ni < 4; ++ni)
          acc[mi][ni] = __builtin_amdgcn_mfma_f32_16x16x32_bf16(
              af[mi], bfv[ni], acc[mi][ni], 0, 0, 0);
    }
    __syncthreads();                            // reads drained before re-stage
  }

  // epilogue: C/D layout col=lane&15, row=(lane>>4)*4+j  [m89-verified]
  const int lr4 = kg * 4;
  #pragma unroll
  for (int mi = 0; mi < 4; ++mi) {
    #pragma unroll
    for (int ni = 0; ni < 4; ++ni) {
      int row = m0 + wr * 64 + mi * 16 + lr4;
      int col = n0 + wc * 64 + ni * 16 + lr16;
      size_t o = (size_t)bz * oBatch + (size_t)row * N + col;
      f32x4 v = acc[mi][ni];
      #pragma unroll
      for (int j = 0; j < 4; ++j) {
        size_t oo = o + (size_t)j * N;
        float x = v[j];
        if (EPI == 0) {
          outBf[oo] = f2bf(x * scale);
        } else if (EPI == 1) {
          outBf[oo] = f2bf(bf2f(auxBf[oo]) + x);
        } else if (EPI == 2) {
          float h = x + bias[col];
          h = h > 0.f ? h : 0.f;
          outBf[oo] = f2bf(h);
        } else {
          outF[oo] = x + bias[col] + bf2f(auxBf[oo]);
        }
      }
    }
  }
}

// ---------------- launch ----------------
extern "C" void kernel_launch(void* const* d_in, const int* in_sizes, int n_in,
                              void* d_out, int out_size, void* d_ws, size_t ws_size,
                              hipStream_t stream) {
  (void)in_sizes; (void)n_in; (void)out_size; (void)ws_size;
  const float* Q  = (const float*)d_in[0];
  const float* Km = (const float*)d_in[1];
  const float* V  = (const float*)d_in[2];
  const float* Vm = (const float*)d_in[3];
  const float* W1 = (const float*)d_in[4];
  const float* b1 = (const float*)d_in[5];
  const float* W2 = (const float*)d_in[6];
  const float* b2 = (const float*)d_in[7];
  float* out = (float*)d_out;

  const int LQ = 1024, LK = 1024, D = 1024;
  const size_t NQ = (size_t)32 * LQ * D;            // 33.5M elems

  // workspace layout (MiB offsets): Qb 0..64, Kb/hb 64..128, Vt 128..192,
  // Sb 192..256, P 256..320, Xb 320..384, W1b 384..386, W2b 386..388
  char* ws = (char*)d_ws;
  ushort* Qb  = (ushort*)(ws);
  ushort* Kb  = (ushort*)(ws + ((size_t)64 << 20));
  ushort* hb  = Kb;                                  // reuse (Kb dead after S-GEMM)
  ushort* Vt  = (ushort*)(ws + ((size_t)128 << 20));
  ushort* Sb  = (ushort*)(ws + ((size_t)192 << 20));
  ushort* P   = (ushort*)(ws + ((size_t)256 << 20));
  ushort* Xb  = (ushort*)(ws + ((size_t)320 << 20));
  ushort* W1b = (ushort*)(ws + ((size_t)384 << 20));
  ushort* W2b = (ushort*)(ws + ((size_t)386 << 20));

  const float inv_scale = 1.0f / (sqrtf(1024.0f) + 1e-8f);

  // paired casts: Q+K in one launch, W1+W2 in one launch
  cast2_f32_bf16<<<dim3(2048, 1, 2), 256, 0, stream>>>(
      (const float4*)Q, (ushort4*)Qb, (const float4*)Km, (ushort4*)Kb, (int)(NQ / 4));
  cast2_f32_bf16<<<dim3(256, 1, 2), 256, 0, stream>>>(
      (const float4*)W1, (ushort4*)W1b, (const float4*)W2, (ushort4*)W2b, (1024 * 1024) / 4);
  transpose_cast_v<<<dim3(32, 32, 32), dim3(32, 8), 0, stream>>>(V, Vt);

  // Sb = bf16((Qb @ Kb^T) * inv_scale), batched over 32
  gemm128<0><<<dim3(8, 8, 32), 256, 0, stream>>>(
      Qb, Kb,
      (size_t)LQ * D, (size_t)LK * D, (size_t)LQ * LK,
      inv_scale, Sb, nullptr, nullptr, nullptr);

  softmax_mask<<<32768, 256, 0, stream>>>(Sb, P, Vm);

  // Xb = bf16(Qb + P @ V)
  gemm128<1><<<dim3(8, 8, 32), 256, 0, stream>>>(
      P, Vt,
      (size_t)LQ * LK, (size_t)D * LK, (size_t)LQ * D,
      1.f, Xb, nullptr, Qb, nullptr);

  // hb = bf16(relu(Xb @ W1^T + b1)); M = 32768 folded into blockIdx.y
  gemm128<2><<<dim3(8, 256, 1), 256, 0, stream>>>(
      Xb, W1b, 0, 0, 0,
      1.f, hb, nullptr, nullptr, b1);

  // out = hb @ W2^T + b2 + Xb
  gemm128<3><<<dim3(8, 256, 1), 256, 0, stream>>>(
      hb, W2b, 0, 0, 0,
      1.f, nullptr, out, Xb, b2);
}

// Round 19
// 527.835 us; speedup vs baseline: 1.0257x; 1.0067x over previous
//
#include <hip/hip_runtime.h>
#include <hip/hip_bf16.h>
#include <stdint.h>
#include <math.h>

// ---------------- types / helpers ----------------
typedef __attribute__((ext_vector_type(8))) short bf16x8;   // 8 bf16 in 4 VGPRs
typedef __attribute__((ext_vector_type(4))) float f32x4;

#define AS1 __attribute__((address_space(1)))
#define AS3 __attribute__((address_space(3)))

__device__ __forceinline__ ushort f2bf(float f) {
  union { float f; uint32_t u; } in; in.f = f;
  uint32_t u = in.u;
  uint32_t r = u + 0x7fffu + ((u >> 16) & 1u);   // RNE; inputs finite
  return (ushort)(r >> 16);
}
__device__ __forceinline__ float bf2f(ushort h) {
  union { uint32_t u; float f; } out; out.u = ((uint32_t)h) << 16;
  return out.f;
}

// ---------------- paired cast f32 -> bf16 (W1+W2, one launch) -------------
__global__ __launch_bounds__(256)
void cast2_f32_bf16(const float4* __restrict__ inA, ushort4* __restrict__ outA,
                    const float4* __restrict__ inB, ushort4* __restrict__ outB,
                    int n4) {
  const float4* in = blockIdx.z ? inB : inA;
  ushort4* out = blockIdx.z ? outB : outA;
  int i = blockIdx.x * blockDim.x + threadIdx.x;
  int stride = gridDim.x * blockDim.x;
  for (; i < n4; i += stride) {
    float4 v = in[i];
    ushort4 o;
    o.x = f2bf(v.x); o.y = f2bf(v.y); o.z = f2bf(v.z); o.w = f2bf(v.w);
    out[i] = o;
  }
}

// ---------------- V (B,LK,D) f32 -> Vt (B,D,LK) bf16, ushort4 stores ------
__global__ __launch_bounds__(256)
void transpose_cast_v(const float* __restrict__ V, ushort* __restrict__ Vt) {
  __shared__ ushort tile[32][36];                // 36-pad: store-gather spread
  const int b  = blockIdx.z;
  const int k0 = blockIdx.x * 32;
  const int d0 = blockIdx.y * 32;
  const int tx = threadIdx.x;                    // 0..31
  const int ty = threadIdx.y;                    // 0..7
  const float* Vb = V + ((size_t)b * 1024 + k0) * 1024 + d0;
  #pragma unroll
  for (int r = 0; r < 4; ++r) {
    int k = ty * 4 + r;
    tile[k][tx] = f2bf(Vb[(size_t)k * 1024 + tx]);
  }
  __syncthreads();
  const int t = ty * 32 + tx;
  const int d = t >> 3, kq = t & 7;
  ushort4 o;
  o.x = tile[kq * 4 + 0][d];
  o.y = tile[kq * 4 + 1][d];
  o.z = tile[kq * 4 + 2][d];
  o.w = tile[kq * 4 + 3][d];
  ushort* Vtb = Vt + ((size_t)b * 1024 + d0) * 1024 + k0;
  *(ushort4*)(Vtb + (size_t)d * 1024 + kq * 4) = o;
}

// ---------------- masked softmax over each (b,q) row of S (bf16 in/out) ----
__global__ __launch_bounds__(256)
void softmax_mask(const ushort* __restrict__ S, ushort* __restrict__ P,
                  const float* __restrict__ mask) {
  const int rowId = blockIdx.x;                  // 0..B*LQ-1
  const int b = rowId >> 10;                     // LQ = 1024
  const ushort4* srow = (const ushort4*)(S + (size_t)rowId * 1024);
  const float4* mrow = (const float4*)(mask + (size_t)b * 1024);
  const int t = threadIdx.x;
  const int wid = t >> 6, lane = t & 63;

  ushort4 sv = srow[t];
  float4 mv = mrow[t];
  float s[4] = {bf2f(sv.x), bf2f(sv.y), bf2f(sv.z), bf2f(sv.w)};
  float m[4] = {mv.x, mv.y, mv.z, mv.w};

  float mx = -INFINITY;
  #pragma unroll
  for (int i = 0; i < 4; ++i) if (m[i] != 0.f) mx = fmaxf(mx, s[i]);
  #pragma unroll
  for (int off = 32; off > 0; off >>= 1)
    mx = fmaxf(mx, __shfl_xor(mx, off));

  __shared__ float wred[4][2];
  if (lane == 0) wred[wid][0] = mx;
  __syncthreads();
  float M = fmaxf(fmaxf(wred[0][0], wred[1][0]), fmaxf(wred[2][0], wred[3][0]));

  float e[4]; float sum = 0.f;
  #pragma unroll
  for (int i = 0; i < 4; ++i) {
    e[i] = (m[i] != 0.f) ? __expf(s[i] - M) : 0.f;
    sum += e[i];
  }
  #pragma unroll
  for (int off = 32; off > 0; off >>= 1)
    sum += __shfl_xor(sum, off);
  if (lane == 0) wred[wid][1] = sum;
  __syncthreads();
  float Z = wred[0][1] + wred[1][1] + wred[2][1] + wred[3][1];
  float inv = (Z > 0.f) ? 1.f / Z : 0.f;

  ushort4 o;
  o.x = f2bf(e[0] * inv); o.y = f2bf(e[1] * inv);
  o.z = f2bf(e[2] * inv); o.w = f2bf(e[3] * inv);
  ((ushort4*)(P + (size_t)rowId * 1024))[t] = o;
}

// ---------------- S-GEMM 128x128 with FUSED f32->bf16 staging -------------
// Sb = bf16((Q @ K^T) * scale).  Q,K are f32; each thread reg-stages
// 8 float4 per matrix per ktile, converts (same RNE f2bf as the old cast
// pass -> bit-identical S), and ds_writes b128 at the SWIZZLED address
// (per-lane stores: swizzle applied directly, read side unchanged from r16).
// Eliminates the 402-MB Q/K cast pass (~64 us of HBM traffic).
// r17 proved the GEMM slot has staging-bandwidth slack -> penalty bounded.
template<int DUMMY>
__global__ __launch_bounds__(256, 4)
void gemm128_qk(const float* __restrict__ A, const float* __restrict__ Bt,
                size_t aBatch, size_t bBatch, size_t oBatch,
                float scale, ushort* outBf)
{
  constexpr int K = 1024, N = 1024, NT = 16;    // K-tiles of 64
  __shared__ ushort lsA[128 * 64];              // 16 KiB
  __shared__ ushort lsB[128 * 64];              // 16 KiB
  const int t = threadIdx.x;
  const int w = t >> 6, lane = t & 63;
  const int wr = w >> 1, wc = w & 1;            // 2 x 2 waves -> 64x64 per wave
  const int lr16 = lane & 15, kg = lane >> 4;

  // T1: XCD-aware bijective remap
  const unsigned nx = gridDim.x, ny = gridDim.y;
  unsigned flat = blockIdx.x + nx * (blockIdx.y + ny * blockIdx.z);
  const unsigned nwg = nx * ny * gridDim.z;
  const unsigned cpx = nwg >> 3;
  unsigned nf = (flat & 7u) * cpx + (flat >> 3);
  const unsigned bxi = nf % nx;
  const unsigned rest = nf / nx;
  const unsigned byi = rest % ny;
  const unsigned bz = rest / ny;
  const int m0 = byi * 128, n0 = bxi * 128;

  const char* Af = (const char*)(A + (size_t)bz * aBatch + (size_t)m0 * K);
  const char* Bf = (const char*)(Bt + (size_t)bz * bBatch + (size_t)n0 * K);

  // staging decode: 4 chunks of 16B-bf16 per matrix per thread.
  // swizzled lds byte y = (w*4+i)*1024 + lane*16 (store target);
  // unswizzled tile byte tb = y ^ ((y>>3)&0x70): row = tb>>7, cb = tb&127;
  // f32 source byte = row*4096 + cb*2 (+ kt*256).
  int fOff[4], yOff[4];
  #pragma unroll
  for (int i = 0; i < 4; ++i) {
    int y = (w * 4 + i) * 1024 + lane * 16;
    int tb = y ^ ((y >> 3) & 0x70);
    fOff[i] = (tb >> 7) * 4096 + (tb & 127) * 2;
    yOff[i] = y;
  }

  // fragment reads (swizzled): row*128 + ((ks*4+kg)^(row&7))*16, row&7 = lr16&7
  const int sl0 = (kg ^ (lr16 & 7)) << 4;
  const int aBase = (wr * 64 + lr16) * 128 + sl0;
  const int bBase = (wc * 64 + lr16) * 128 + sl0;

  f32x4 acc[4][4];
  #pragma unroll
  for (int i = 0; i < 4; ++i)
    #pragma unroll
    for (int j = 0; j < 4; ++j)
      acc[i][j] = (f32x4){0.f, 0.f, 0.f, 0.f};

  #pragma unroll 1
  for (int kt = 0; kt < NT; ++kt) {
    // reg-stage + convert both tiles (8 float4 loads + 4 b128 stores / matrix)
    #pragma unroll
    for (int i = 0; i < 4; ++i) {
      const char* sa = Af + fOff[i] + kt * 256;
      float4 a0 = *(const float4*)(sa);
      float4 a1 = *(const float4*)(sa + 16);
      const char* sb = Bf + fOff[i] + kt * 256;
      float4 b0 = *(const float4*)(sb);
      float4 b1 = *(const float4*)(sb + 16);
      bf16x8 pa, pb;
      pa[0] = (short)f2bf(a0.x); pa[1] = (short)f2bf(a0.y);
      pa[2] = (short)f2bf(a0.z); pa[3] = (short)f2bf(a0.w);
      pa[4] = (short)f2bf(a1.x); pa[5] = (short)f2bf(a1.y);
      pa[6] = (short)f2bf(a1.z); pa[7] = (short)f2bf(a1.w);
      pb[0] = (short)f2bf(b0.x); pb[1] = (short)f2bf(b0.y);
      pb[2] = (short)f2bf(b0.z); pb[3] = (short)f2bf(b0.w);
      pb[4] = (short)f2bf(b1.x); pb[5] = (short)f2bf(b1.y);
      pb[6] = (short)f2bf(b1.z); pb[7] = (short)f2bf(b1.w);
      *(bf16x8*)((char*)lsA + yOff[i]) = pa;
      *(bf16x8*)((char*)lsB + yOff[i]) = pb;
    }
    __syncthreads();                            // writes visible to all waves

    #pragma unroll
    for (int ks = 0; ks < 2; ++ks) {
      bf16x8 af[4], bfv[4];
      #pragma unroll
      for (int mi = 0; mi < 4; ++mi)
        af[mi] = *(const bf16x8*)((const char*)lsA + ((aBase + mi * 2048) ^ (ks * 64)));
      #pragma unroll
      for (int ni = 0; ni < 4; ++ni)
        bfv[ni] = *(const bf16x8*)((const char*)lsB + ((bBase + ni * 2048) ^ (ks * 64)));
      #pragma unroll
      for (int mi = 0; mi < 4; ++mi)
        #pragma unroll
        for (int ni = 0; ni < 4; ++ni)
          acc[mi][ni] = __builtin_amdgcn_mfma_f32_16x16x32_bf16(
              af[mi], bfv[ni], acc[mi][ni], 0, 0, 0);
    }
    __syncthreads();                            // reads drained before re-stage
  }

  // epilogue: C/D layout col=lane&15, row=(lane>>4)*4+j
  const int lr4 = kg * 4;
  #pragma unroll
  for (int mi = 0; mi < 4; ++mi) {
    #pragma unroll
    for (int ni = 0; ni < 4; ++ni) {
      int row = m0 + wr * 64 + mi * 16 + lr4;
      int col = n0 + wc * 64 + ni * 16 + lr16;
      size_t o = (size_t)bz * oBatch + (size_t)row * N + col;
      f32x4 v = acc[mi][ni];
      #pragma unroll
      for (int j = 0; j < 4; ++j)
        outBf[o + (size_t)j * N] = f2bf(v[j] * scale);
    }
  }
}

// ---------------- GEMM 128x128, BK=64, 4 waves, single-buffer (r9/r16) ----
// EPI: 1 -> outBf = bf16(auxF + acc)                             (X = Q + PV)
//      2 -> outBf = bf16(relu(acc + bias[col]))                  (FFN1 -> h)
//      3 -> outF  = acc + bias[col] + bf2f(auxBf)                (FFN2 + residual)
template<int EPI>
__global__ __launch_bounds__(256, 4)
void gemm128(const ushort* __restrict__ A, const ushort* __restrict__ Bt,
             size_t aBatch, size_t bBatch, size_t oBatch,
             float scale,
             ushort* outBf, float* outF, const ushort* auxBf,
             const float* __restrict__ auxF,
             const float* __restrict__ bias)
{
  constexpr int K = 1024, N = 1024, NT = 16;    // K-tiles of 64
  __shared__ ushort lsA[128 * 64];              // 16 KiB
  __shared__ ushort lsB[128 * 64];              // 16 KiB
  const int t = threadIdx.x;
  const int w = t >> 6, lane = t & 63;
  const int wr = w >> 1, wc = w & 1;            // 2 x 2 waves -> 64x64 per wave
  const int lr16 = lane & 15, kg = lane >> 4;

  // T1: XCD-aware bijective remap
  const unsigned nx = gridDim.x, ny = gridDim.y;
  unsigned flat = blockIdx.x + nx * (blockIdx.y + ny * blockIdx.z);
  const unsigned nwg = nx * ny * gridDim.z;
  const unsigned cpx = nwg >> 3;
  unsigned nf = (flat & 7u) * cpx + (flat >> 3);
  const unsigned bxi = nf % nx;
  const unsigned rest = nf / nx;
  const unsigned byi = rest % ny;
  const unsigned bz = rest / ny;
  const int m0 = byi * 128, n0 = bxi * 128;

  const char* Ab = (const char*)(A + (size_t)bz * aBatch + (size_t)m0 * K);
  const char* Bb = (const char*)(Bt + (size_t)bz * bBatch + (size_t)n0 * K);

  int gOff[4], lOff[4];
  #pragma unroll
  for (int i = 0; i < 4; ++i) {
    int y = (w * 4 + i) * 1024 + lane * 16;
    int tb = y ^ ((y >> 3) & 0x70);
    gOff[i] = (tb >> 7) * 2048 + (tb & 127);
    lOff[i] = (w * 4 + i) * 1024;               // wave-uniform LDS base (+lane*16 by HW)
  }

  const int sl0 = (kg ^ (lr16 & 7)) << 4;
  const int aBase = (wr * 64 + lr16) * 128 + sl0;
  const int bBase = (wc * 64 + lr16) * 128 + sl0;

  f32x4 acc[4][4];
  #pragma unroll
  for (int i = 0; i < 4; ++i)
    #pragma unroll
    for (int j = 0; j < 4; ++j)
      acc[i][j] = (f32x4){0.f, 0.f, 0.f, 0.f};

  #pragma unroll 1
  for (int kt = 0; kt < NT; ++kt) {
    #pragma unroll
    for (int i = 0; i < 4; ++i)
      __builtin_amdgcn_global_load_lds(
        (const AS1 void*)(Ab + gOff[i] + kt * 128),
        (AS3 void*)((char*)lsA + lOff[i]), 16, 0, 0);
    #pragma unroll
    for (int i = 0; i < 4; ++i)
      __builtin_amdgcn_global_load_lds(
        (const AS1 void*)(Bb + gOff[i] + kt * 128),
        (AS3 void*)((char*)lsB + lOff[i]), 16, 0, 0);
    __syncthreads();                            // compiler: vmcnt(0) drain

    #pragma unroll
    for (int ks = 0; ks < 2; ++ks) {
      bf16x8 af[4], bfv[4];
      #pragma unroll
      for (int mi = 0; mi < 4; ++mi)
        af[mi] = *(const bf16x8*)((const char*)lsA + ((aBase + mi * 2048) ^ (ks * 64)));
      #pragma unroll
      for (int ni = 0; ni < 4; ++ni)
        bfv[ni] = *(const bf16x8*)((const char*)lsB + ((bBase + ni * 2048) ^ (ks * 64)));
      #pragma unroll
      for (int mi = 0; mi < 4; ++mi)
        #pragma unroll
        for (int ni = 0; ni < 4; ++ni)
          acc[mi][ni] = __builtin_amdgcn_mfma_f32_16x16x32_bf16(
              af[mi], bfv[ni], acc[mi][ni], 0, 0, 0);
    }
    __syncthreads();                            // reads drained before re-stage
  }

  const int lr4 = kg * 4;
  #pragma unroll
  for (int mi = 0; mi < 4; ++mi) {
    #pragma unroll
    for (int ni = 0; ni < 4; ++ni) {
      int row = m0 + wr * 64 + mi * 16 + lr4;
      int col = n0 + wc * 64 + ni * 16 + lr16;
      size_t o = (size_t)bz * oBatch + (size_t)row * N + col;
      f32x4 v = acc[mi][ni];
      #pragma unroll
      for (int j = 0; j < 4; ++j) {
        size_t oo = o + (size_t)j * N;
        float x = v[j];
        if (EPI == 1) {
          outBf[oo] = f2bf(auxF[oo] + x);
        } else if (EPI == 2) {
          float h = x + bias[col];
          h = h > 0.f ? h : 0.f;
          outBf[oo] = f2bf(h);
        } else {
          outF[oo] = x + bias[col] + bf2f(auxBf[oo]);
        }
      }
    }
  }
}

// ---------------- launch ----------------
extern "C" void kernel_launch(void* const* d_in, const int* in_sizes, int n_in,
                              void* d_out, int out_size, void* d_ws, size_t ws_size,
                              hipStream_t stream) {
  (void)in_sizes; (void)n_in; (void)out_size; (void)ws_size;
  const float* Q  = (const float*)d_in[0];
  const float* Km = (const float*)d_in[1];
  const float* V  = (const float*)d_in[2];
  const float* Vm = (const float*)d_in[3];
  const float* W1 = (const float*)d_in[4];
  const float* b1 = (const float*)d_in[5];
  const float* W2 = (const float*)d_in[6];
  const float* b2 = (const float*)d_in[7];
  float* out = (float*)d_out;

  const int LQ = 1024, LK = 1024, D = 1024;

  // workspace layout (MiB offsets): hb 64..128, Vt 128..192, Sb 192..256,
  // P 256..320, Xb 320..384, W1b 384..386, W2b 386..388
  char* ws = (char*)d_ws;
  ushort* hb  = (ushort*)(ws + ((size_t)64 << 20));
  ushort* Vt  = (ushort*)(ws + ((size_t)128 << 20));
  ushort* Sb  = (ushort*)(ws + ((size_t)192 << 20));
  ushort* P   = (ushort*)(ws + ((size_t)256 << 20));
  ushort* Xb  = (ushort*)(ws + ((size_t)320 << 20));
  ushort* W1b = (ushort*)(ws + ((size_t)384 << 20));
  ushort* W2b = (ushort*)(ws + ((size_t)386 << 20));

  const float inv_scale = 1.0f / (sqrtf(1024.0f) + 1e-8f);

  cast2_f32_bf16<<<dim3(256, 1, 2), 256, 0, stream>>>(
      (const float4*)W1, (ushort4*)W1b, (const float4*)W2, (ushort4*)W2b, (1024 * 1024) / 4);
  transpose_cast_v<<<dim3(32, 32, 32), dim3(32, 8), 0, stream>>>(V, Vt);

  // Sb = bf16((Q @ K^T) * inv_scale), f32 inputs, fused cast in staging
  gemm128_qk<0><<<dim3(8, 8, 32), 256, 0, stream>>>(
      Q, Km,
      (size_t)LQ * D, (size_t)LK * D, (size_t)LQ * LK,
      inv_scale, Sb);

  softmax_mask<<<32768, 256, 0, stream>>>(Sb, P, Vm);

  // Xb = bf16(Q + P @ V)   (residual read from f32 Q directly)
  gemm128<1><<<dim3(8, 8, 32), 256, 0, stream>>>(
      P, Vt,
      (size_t)LQ * LK, (size_t)D * LK, (size_t)LQ * D,
      1.f, Xb, nullptr, nullptr, Q, nullptr);

  // hb = bf16(relu(Xb @ W1^T + b1)); M = 32768 folded into blockIdx.y
  gemm128<2><<<dim3(8, 256, 1), 256, 0, stream>>>(
      Xb, W1b, 0, 0, 0,
      1.f, hb, nullptr, nullptr, nullptr, b1);

  // out = hb @ W2^T + b2 + Xb
  gemm128<3><<<dim3(8, 256, 1), 256, 0, stream>>>(
      hb, W2b, 0, 0, 0,
      1.f, nullptr, out, Xb, nullptr, b2);
}